// Round 3
// baseline (2830.202 us; speedup 1.0000x reference)
//
#include <hip/hip_runtime.h>
#include <hip/hip_bf16.h>

#define D 128
#define GEMM_ROWS_PER_BLOCK 32

typedef unsigned int uint;

// unpack a bf16x2 (as uint) into two floats: x = low half, y = high half
static __device__ __forceinline__ float2 bf16x2(uint u) {
  float2 r;
  r.x = __uint_as_float(u << 16);
  r.y = __uint_as_float(u & 0xffff0000u);
  return r;
}

static __device__ __forceinline__ uint pack_bf16x2(float a, float b) {
  __hip_bfloat162 o;
  o.x = __float2bfloat16(a);
  o.y = __float2bfloat16(b);
  return *reinterpret_cast<uint*>(&o);
}

// load element-pair j2 of row `row` from a [M][128] float matrix whose true
// storage is fp32 (isf=1) or packed bf16 (isf=0)
static __device__ __forceinline__ float2 load_pair(const void* X, size_t idx,
                                                   int isf) {
  if (isf) return ((const float2*)X)[idx];
  return bf16x2(((const uint*)X)[idx]);
}

// ---------------------------------------------------------------------------
// Detect input dtype. bf16 N(0,1) data -> max|pair| ~ 5. fp32 data misread as
// bf16 pairs -> low halves are random-exponent garbage -> max >> 1e6.
// flag = 1 means fp32 storage.
// ---------------------------------------------------------------------------
__global__ void detect_kernel(const uint* __restrict__ x, int n_words,
                              int* __restrict__ flag) {
  __shared__ float smax[256];
  float m = 0.f;
  for (int i = threadIdx.x; i < n_words; i += 256) {
    float2 v = bf16x2(x[i]);
    float a = fabsf(v.x);
    float b = fabsf(v.y);
    if (!(a <= 1e30f)) a = 1e30f;  // NaN/inf -> large
    if (!(b <= 1e30f)) b = 1e30f;
    m = fmaxf(m, fmaxf(a, b));
  }
  smax[threadIdx.x] = m;
  __syncthreads();
  for (int s = 128; s > 0; s >>= 1) {
    if (threadIdx.x < s)
      smax[threadIdx.x] = fmaxf(smax[threadIdx.x], smax[threadIdx.x + s]);
    __syncthreads();
  }
  if (threadIdx.x == 0) *flag = (smax[0] > 1e6f) ? 1 : 0;
}

// ---------------------------------------------------------------------------
// Histogram of edge destinations: deg (PPI col) and cnt (DTI prot)
// ---------------------------------------------------------------------------
__global__ void count_kernel(const int* __restrict__ ppi_col,
                             const int* __restrict__ dti_prot,
                             int* __restrict__ deg, int* __restrict__ cnt,
                             int e_ppi, int e_dti, int n_prot) {
  int i = blockIdx.x * blockDim.x + threadIdx.x;
  if (i < e_ppi) {
    int c = ppi_col[i];
    if ((unsigned)c < (unsigned)n_prot) atomicAdd(&deg[c], 1);
  } else if (i < e_ppi + e_dti) {
    int c = dti_prot[i - e_ppi];
    if ((unsigned)c < (unsigned)n_prot) atomicAdd(&cnt[c], 1);
  }
}

__global__ void dinv_kernel(const int* __restrict__ deg,
                            const int* __restrict__ cnt,
                            float* __restrict__ dinv,
                            float* __restrict__ invcnt, int n) {
  int i = blockIdx.x * blockDim.x + threadIdx.x;
  if (i < n) {
    // reference deg = (#edges with col==i) + 1 self-loop, always > 0
    dinv[i] = rsqrtf((float)(deg[i] + 1));
    invcnt[i] = 1.0f / fmaxf((float)cnt[i], 1.0f);
  }
}

// ---------------------------------------------------------------------------
// Y[M,128] (fp32) = X[M,128] @ W[128,128] (+ bias). X/W/bias dtype per flag.
// W staged in LDS as float2 (64 KB). One row per wave; X row broadcast via
// shuffles; lane = column pair. No per-row __syncthreads.
// ---------------------------------------------------------------------------
__global__ __launch_bounds__(256) void gemm_kernel(
    const void* __restrict__ X, const void* __restrict__ W,
    const void* __restrict__ bias, float* __restrict__ Y,
    const int* __restrict__ flag, int M) {
  __shared__ float2 Wf[D][D / 2];  // 64 KB
  int isf = *flag;
  int tid = threadIdx.x;
  int j2 = tid & 63, sub = tid >> 6;
  for (int idx = tid; idx < D * (D / 2); idx += 256)
    Wf[idx >> 6][idx & 63] = load_pair(W, idx, isf);
  float2 b = make_float2(0.f, 0.f);
  if (bias) b = load_pair(bias, j2, isf);
  __syncthreads();

  int blockRow = blockIdx.x * GEMM_ROWS_PER_BLOCK;
  for (int r = sub; r < GEMM_ROWS_PER_BLOCK; r += 4) {
    int row = blockRow + r;
    if (row >= M) break;
    float2 xv = load_pair(X, (size_t)row * 64 + j2, isf);
    float ax = 0.f, ay = 0.f;
#pragma unroll 16
    for (int kk = 0; kk < 64; ++kk) {
      float xa = __shfl(xv.x, kk);
      float xb = __shfl(xv.y, kk);
      float2 w0 = Wf[2 * kk][j2];
      float2 w1 = Wf[2 * kk + 1][j2];
      ax = fmaf(xa, w0.x, fmaf(xb, w1.x, ax));
      ay = fmaf(xa, w0.y, fmaf(xb, w1.y, ay));
    }
    ((float2*)Y)[(size_t)row * 64 + j2] = make_float2(ax + b.x, ay + b.y);
  }
}

// ---------------------------------------------------------------------------
// Edge scatter into fp32 acc for destination rows [lo, hi).
// One wave per edge; lane handles a column pair.
// PPI: acc[col] += xw[row] * dinv[row]*dinv[col]
// DTI: acc[prot] += yd[drug] * invcnt[prot]
// ---------------------------------------------------------------------------
__global__ __launch_bounds__(256) void scatter_kernel(
    const int* __restrict__ ppi_row, const int* __restrict__ ppi_col,
    const int* __restrict__ dti_drug, const int* __restrict__ dti_prot,
    const float* __restrict__ xw, const float* __restrict__ yd,
    const float* __restrict__ dinv, const float* __restrict__ invcnt,
    float* __restrict__ acc, int e_ppi, int e_dti, int lo, int hi, int n_prot,
    int n_drug, int totalWaves) {
  int wid = (blockIdx.x * blockDim.x + threadIdx.x) >> 6;
  int lane = threadIdx.x & 63;
  int total = e_ppi + e_dti;
  for (int e = wid; e < total; e += totalWaves) {
    if (e < e_ppi) {
      int dst = ppi_col[e];
      if (dst < lo || dst >= hi) continue;
      int src = ppi_row[e];
      if ((unsigned)src >= (unsigned)n_prot) continue;  // defensive
      float c = dinv[src] * dinv[dst];
      float2 v = ((const float2*)xw)[(size_t)src * 64 + lane];
      float* p = &acc[(size_t)(dst - lo) * D + 2 * lane];
      unsafeAtomicAdd(p, v.x * c);
      unsafeAtomicAdd(p + 1, v.y * c);
    } else {
      int ed = e - e_ppi;
      int dst = dti_prot[ed];
      if (dst < lo || dst >= hi) continue;
      int src = dti_drug[ed];
      if ((unsigned)src >= (unsigned)n_drug) continue;  // defensive
      float c = invcnt[dst];
      float2 v = ((const float2*)yd)[(size_t)src * 64 + lane];
      float* p = &acc[(size_t)(dst - lo) * D + 2 * lane];
      unsafeAtomicAdd(p, v.x * c);
      unsafeAtomicAdd(p + 1, v.y * c);
    }
  }
}

// ---------------------------------------------------------------------------
// Fused: x3 = x_prot@W_pr (+b_pr), v = acc + xw*dinv^2 + x3 + b_gcn + 1e-6,
// then LayerNorm. Output dtype per flag. Processes rows [lo, hi).
// ---------------------------------------------------------------------------
__global__ __launch_bounds__(256) void gemm_ln_kernel(
    const void* __restrict__ X, const void* __restrict__ Wpr,
    const float* __restrict__ acc, const float* __restrict__ xw,
    const float* __restrict__ dinv, const void* __restrict__ bg,
    const void* __restrict__ bp, void* __restrict__ out,
    const int* __restrict__ flag, int lo, int hi) {
  __shared__ float2 Wf[D][D / 2];  // 64 KB
  int isf = *flag;
  int tid = threadIdx.x;
  int j2 = tid & 63, sub = tid >> 6;
  for (int idx = tid; idx < D * (D / 2); idx += 256)
    Wf[idx >> 6][idx & 63] = load_pair(Wpr, idx, isf);
  float2 bgv = load_pair(bg, j2, isf);
  float2 bpv = load_pair(bp, j2, isf);
  __syncthreads();

  int blockRow = lo + blockIdx.x * GEMM_ROWS_PER_BLOCK;
  for (int r = sub; r < GEMM_ROWS_PER_BLOCK; r += 4) {
    int row = blockRow + r;
    if (row >= hi) break;
    float2 xv = load_pair(X, (size_t)row * 64 + j2, isf);
    float ax = 0.f, ay = 0.f;
#pragma unroll 16
    for (int kk = 0; kk < 64; ++kk) {
      float xa = __shfl(xv.x, kk);
      float xb = __shfl(xv.y, kk);
      float2 w0 = Wf[2 * kk][j2];
      float2 w1 = Wf[2 * kk + 1][j2];
      ax = fmaf(xa, w0.x, fmaf(xb, w1.x, ax));
      ay = fmaf(xa, w0.y, fmaf(xb, w1.y, ay));
    }
    float2 a = ((const float2*)acc)[(size_t)(row - lo) * 64 + j2];
    float2 xwv = ((const float2*)xw)[(size_t)row * 64 + j2];
    float di = dinv[row];
    float sc = di * di;  // self-loop norm
    float v0 = a.x + xwv.x * sc + ax + bpv.x + bgv.x + 1e-6f;
    float v1 = a.y + xwv.y * sc + ay + bpv.y + bgv.y + 1e-6f;
    float s = v0 + v1, ss = v0 * v0 + v1 * v1;
    for (int off = 1; off < 64; off <<= 1) {
      s += __shfl_xor(s, off);
      ss += __shfl_xor(ss, off);
    }
    float mu = s * (1.0f / 128.0f);
    float var = ss * (1.0f / 128.0f) - mu * mu;
    float rs = rsqrtf(var + 1e-5f);
    float o0 = (v0 - mu) * rs, o1 = (v1 - mu) * rs;
    if (isf)
      ((float2*)out)[(size_t)row * 64 + j2] = make_float2(o0, o1);
    else
      ((uint*)out)[(size_t)row * 64 + j2] = pack_bf16x2(o0, o1);
  }
}

// ---------------------------------------------------------------------------
extern "C" void kernel_launch(void* const* d_in, const int* in_sizes, int n_in,
                              void* d_out, int out_size, void* d_ws,
                              size_t ws_size, hipStream_t stream) {
  const void* x_prot = d_in[0];
  const void* x_drug = d_in[1];
  const void* W_gcn = d_in[2];
  const void* b_gcn = d_in[3];
  const void* W_td = d_in[4];
  const void* b_td = d_in[5];
  const void* W_pr = d_in[6];
  const void* b_pr = d_in[7];
  const int* ppi = (const int*)d_in[8];
  const int* dti_drug = (const int*)d_in[9];
  const int* dti_prot = (const int*)d_in[10];

  int n_prot = in_sizes[0] / D;
  int n_drug = in_sizes[1] / D;
  int e_ppi = in_sizes[8] / 2;
  int e_dti = in_sizes[9];

  char* ws = (char*)d_ws;
  size_t off = 0;
  auto alloc = [&](size_t bytes) {
    void* p = ws + off;
    off = (off + bytes + 255) & ~(size_t)255;
    return p;
  };
  int* flag = (int*)alloc(256);
  float* xw = (float*)alloc((size_t)n_prot * D * 4);   // 51.2 MB
  float* yd = (float*)alloc((size_t)n_drug * D * 4);   // 10.2 MB
  int* deg = (int*)alloc((size_t)n_prot * 4);
  int* cnt = (int*)alloc((size_t)n_prot * 4);
  float* dinv = (float*)alloc((size_t)n_prot * 4);
  float* invcnt = (float*)alloc((size_t)n_prot * 4);
  float* acc = (float*)(ws + off);  // remainder of workspace

  if (off > ws_size) return;  // ws too small for fixed buffers: bail cleanly
  size_t avail = ws_size - off;
  size_t rows_fit = avail / (D * sizeof(float));
  int chunk_rows = (int)(rows_fit < (size_t)n_prot ? rows_fit : (size_t)n_prot);
  if (chunk_rows < 1) return;  // no room for any accumulator rows
  int nchunks = (n_prot + chunk_rows - 1) / chunk_rows;

  detect_kernel<<<1, 256, 0, stream>>>((const uint*)x_prot, 4096, flag);

  hipMemsetAsync(deg, 0, (size_t)n_prot * 4, stream);
  hipMemsetAsync(cnt, 0, (size_t)n_prot * 4, stream);

  int totE = e_ppi + e_dti;
  count_kernel<<<(totE + 255) / 256, 256, 0, stream>>>(
      ppi + e_ppi, dti_prot, deg, cnt, e_ppi, e_dti, n_prot);
  dinv_kernel<<<(n_prot + 255) / 256, 256, 0, stream>>>(deg, cnt, dinv, invcnt,
                                                        n_prot);

  int gblocks_p = (n_prot + GEMM_ROWS_PER_BLOCK - 1) / GEMM_ROWS_PER_BLOCK;
  int gblocks_d = (n_drug + GEMM_ROWS_PER_BLOCK - 1) / GEMM_ROWS_PER_BLOCK;
  gemm_kernel<<<gblocks_p, 256, 0, stream>>>(x_prot, W_gcn, nullptr, xw, flag,
                                             n_prot);
  gemm_kernel<<<gblocks_d, 256, 0, stream>>>(x_drug, W_td, b_td, yd, flag,
                                             n_drug);

  const int sblocks = 8192;  // 32768 waves grid-striding the edge list
  for (int c = 0; c < nchunks; ++c) {
    int lo = c * chunk_rows;
    int hi = lo + chunk_rows < n_prot ? lo + chunk_rows : n_prot;
    hipMemsetAsync(acc, 0, (size_t)(hi - lo) * D * sizeof(float), stream);
    scatter_kernel<<<sblocks, 256, 0, stream>>>(
        ppi, ppi + e_ppi, dti_drug, dti_prot, xw, yd, dinv, invcnt, acc, e_ppi,
        e_dti, lo, hi, n_prot, n_drug, sblocks * 4);
    int lblocks = (hi - lo + GEMM_ROWS_PER_BLOCK - 1) / GEMM_ROWS_PER_BLOCK;
    gemm_ln_kernel<<<lblocks, 256, 0, stream>>>(x_prot, W_pr, acc, xw, dinv,
                                                b_gcn, b_pr, d_out, flag, lo,
                                                hi);
  }
}

// Round 4
// 1189.937 us; speedup vs baseline: 2.3784x; 2.3784x over previous
//
#include <hip/hip_runtime.h>
#include <hip/hip_bf16.h>

#define D 128
#define ROWS_PER_BLOCK 32

typedef unsigned int uint;

// unpack a bf16x2 (as uint) into two floats: x = low half, y = high half
static __device__ __forceinline__ float2 bf16x2(uint u) {
  float2 r;
  r.x = __uint_as_float(u << 16);
  r.y = __uint_as_float(u & 0xffff0000u);
  return r;
}

static __device__ __forceinline__ uint pack_bf16x2(float a, float b) {
  __hip_bfloat162 o;
  o.x = __float2bfloat16(a);
  o.y = __float2bfloat16(b);
  return *reinterpret_cast<uint*>(&o);
}

// load element-pair idx from a float matrix stored fp32 (isf=1) or bf16 (isf=0)
static __device__ __forceinline__ float2 load_pair(const void* X, size_t idx,
                                                   int isf) {
  if (isf) return ((const float2*)X)[idx];
  return bf16x2(((const uint*)X)[idx]);
}

// ---------------------------------------------------------------------------
// Detect input dtype (bf16 vs fp32 storage). flag=1 means fp32.
// ---------------------------------------------------------------------------
__global__ void detect_kernel(const uint* __restrict__ x, int n_words,
                              int* __restrict__ flag) {
  __shared__ float smax[256];
  float m = 0.f;
  for (int i = threadIdx.x; i < n_words; i += 256) {
    float2 v = bf16x2(x[i]);
    float a = fabsf(v.x), b = fabsf(v.y);
    if (!(a <= 1e30f)) a = 1e30f;
    if (!(b <= 1e30f)) b = 1e30f;
    m = fmaxf(m, fmaxf(a, b));
  }
  smax[threadIdx.x] = m;
  __syncthreads();
  for (int s = 128; s > 0; s >>= 1) {
    if (threadIdx.x < s)
      smax[threadIdx.x] = fmaxf(smax[threadIdx.x], smax[threadIdx.x + s]);
    __syncthreads();
  }
  if (threadIdx.x == 0) *flag = (smax[0] > 1e6f) ? 1 : 0;
}

// ---------------------------------------------------------------------------
// Histogram of edge destinations: deg (PPI col), cnt (DTI prot)
// ---------------------------------------------------------------------------
__global__ void count_kernel(const int* __restrict__ ppi_col,
                             const int* __restrict__ dti_prot,
                             int* __restrict__ deg, int* __restrict__ cnt,
                             int e_ppi, int e_dti, int n_prot) {
  int i = blockIdx.x * blockDim.x + threadIdx.x;
  if (i < e_ppi) {
    int c = ppi_col[i];
    if ((unsigned)c < (unsigned)n_prot) atomicAdd(&deg[c], 1);
  } else if (i < e_ppi + e_dti) {
    int c = dti_prot[i - e_ppi];
    if ((unsigned)c < (unsigned)n_prot) atomicAdd(&cnt[c], 1);
  }
}

__global__ void dinv_kernel(const int* __restrict__ deg,
                            const int* __restrict__ cnt,
                            float* __restrict__ dinv,
                            float* __restrict__ invcnt,
                            int* __restrict__ tot, int n) {
  int i = blockIdx.x * blockDim.x + threadIdx.x;
  if (i < n) {
    dinv[i] = rsqrtf((float)(deg[i] + 1));  // +1 self-loop
    invcnt[i] = 1.0f / fmaxf((float)cnt[i], 1.0f);
    tot[i] = deg[i] + cnt[i];
  }
}

// ---------------------------------------------------------------------------
// Exclusive scan of tot -> offsets (3-kernel scheme)
// ---------------------------------------------------------------------------
__global__ void block_sum_kernel(const int* __restrict__ tot, int n,
                                 int* __restrict__ bsum) {
  __shared__ int sh[256];
  int i = blockIdx.x * 256 + threadIdx.x;
  sh[threadIdx.x] = (i < n) ? tot[i] : 0;
  __syncthreads();
  for (int s = 128; s > 0; s >>= 1) {
    if (threadIdx.x < s) sh[threadIdx.x] += sh[threadIdx.x + s];
    __syncthreads();
  }
  if (threadIdx.x == 0) bsum[blockIdx.x] = sh[0];
}

// single block: in-place exclusive scan of bsum[0..nb)
__global__ void scan_bsums_kernel(int* __restrict__ bsum, int nb) {
  __shared__ int sh[1024];
  __shared__ int carry;
  int tid = threadIdx.x;
  if (tid == 0) carry = 0;
  __syncthreads();
  for (int base = 0; base < nb; base += 1024) {
    int i = base + tid;
    int v = (i < nb) ? bsum[i] : 0;
    sh[tid] = v;
    __syncthreads();
    for (int ofs = 1; ofs < 1024; ofs <<= 1) {
      int t = (tid >= ofs) ? sh[tid - ofs] : 0;
      __syncthreads();
      sh[tid] += t;
      __syncthreads();
    }
    if (i < nb) bsum[i] = carry + sh[tid] - v;  // exclusive
    int total = sh[1023];
    __syncthreads();
    if (tid == 0) carry += total;
    __syncthreads();
  }
}

__global__ void scan_final_kernel(const int* __restrict__ tot,
                                  const int* __restrict__ bbase,
                                  int* __restrict__ offsets, int n) {
  __shared__ int sh[256];
  int tid = threadIdx.x;
  int i = blockIdx.x * 256 + tid;
  int v = (i < n) ? tot[i] : 0;
  sh[tid] = v;
  __syncthreads();
  for (int ofs = 1; ofs < 256; ofs <<= 1) {
    int t = (tid >= ofs) ? sh[tid - ofs] : 0;
    __syncthreads();
    sh[tid] += t;
    __syncthreads();
  }
  if (i < n) {
    int excl = bbase[blockIdx.x] + sh[tid] - v;
    offsets[i] = excl;
    if (i == n - 1) offsets[n] = excl + v;
  }
}

// ---------------------------------------------------------------------------
// Fill CSR: entry = src | (is_dti << 31), grouped by destination node.
// ---------------------------------------------------------------------------
__global__ void fill_kernel(const int* __restrict__ ppi_row,
                            const int* __restrict__ ppi_col,
                            const int* __restrict__ dti_drug,
                            const int* __restrict__ dti_prot,
                            const int* __restrict__ offsets,
                            int* __restrict__ fpos, uint* __restrict__ csr,
                            int e_ppi, int e_dti, int n_prot) {
  int i = blockIdx.x * blockDim.x + threadIdx.x;
  if (i < e_ppi) {
    int dst = ppi_col[i];
    if ((unsigned)dst >= (unsigned)n_prot) return;
    int pos = offsets[dst] + atomicAdd(&fpos[dst], 1);
    csr[pos] = (uint)ppi_row[i];
  } else if (i < e_ppi + e_dti) {
    int j = i - e_ppi;
    int dst = dti_prot[j];
    if ((unsigned)dst >= (unsigned)n_prot) return;
    int pos = offsets[dst] + atomicAdd(&fpos[dst], 1);
    csr[pos] = (uint)dti_drug[j] | 0x80000000u;
  }
}

// ---------------------------------------------------------------------------
// Y2[M][64] (packed bf16 pairs) = X[M,128] @ W[128,128] (+ bias).
// W staged in LDS packed bf16 (32 KB). One row per wave; X row broadcast via
// shuffles; lane = column pair.
// ---------------------------------------------------------------------------
__global__ __launch_bounds__(256) void gemm_kernel(
    const void* __restrict__ X, const void* __restrict__ W,
    const void* __restrict__ bias, uint* __restrict__ Y2,
    const int* __restrict__ flag, int M) {
  __shared__ uint Wp[D][D / 2];  // 32 KB packed bf16
  int isf = *flag;
  int tid = threadIdx.x;
  int j2 = tid & 63, sub = tid >> 6;
  for (int idx = tid; idx < D * (D / 2); idx += 256) {
    float2 w = load_pair(W, idx, isf);
    Wp[idx >> 6][idx & 63] = pack_bf16x2(w.x, w.y);
  }
  float2 b = make_float2(0.f, 0.f);
  if (bias) b = load_pair(bias, j2, isf);
  __syncthreads();

  int blockRow = blockIdx.x * ROWS_PER_BLOCK;
  for (int r = sub; r < ROWS_PER_BLOCK; r += 4) {
    int row = blockRow + r;
    if (row >= M) break;
    float2 xv = load_pair(X, (size_t)row * 64 + j2, isf);
    float ax = 0.f, ay = 0.f;
#pragma unroll 16
    for (int kk = 0; kk < 64; ++kk) {
      float xa = __shfl(xv.x, kk);
      float xb = __shfl(xv.y, kk);
      float2 w0 = bf16x2(Wp[2 * kk][j2]);
      float2 w1 = bf16x2(Wp[2 * kk + 1][j2]);
      ax = fmaf(xa, w0.x, fmaf(xb, w1.x, ax));
      ay = fmaf(xa, w0.y, fmaf(xb, w1.y, ay));
    }
    Y2[(size_t)row * 64 + j2] = pack_bf16x2(ax + b.x, ay + b.y);
  }
}

// ---------------------------------------------------------------------------
// Fused gather + x3-GEMM + LayerNorm. One wave per node:
//  acc = sum_{e in CSR[node]} row(e) * coeff(e)      (register accumulate)
//  v = acc + xw[node]*dinv^2 + x_prot[node]@W_pr + b_pr + b_gcn + 1e-6
//  out[node] = LayerNorm(v)
// ---------------------------------------------------------------------------
__global__ __launch_bounds__(256) void gather_ln_kernel(
    const void* __restrict__ X, const void* __restrict__ Wpr,
    const uint* __restrict__ xw2, const uint* __restrict__ yd2,
    const float* __restrict__ dinv, const float* __restrict__ invcnt,
    const int* __restrict__ offsets, const uint* __restrict__ csr,
    const void* __restrict__ bg, const void* __restrict__ bp,
    void* __restrict__ out, const int* __restrict__ flag, int n_prot) {
  __shared__ uint Wp[D][D / 2];  // 32 KB packed bf16
  int isf = *flag;
  int tid = threadIdx.x;
  int j2 = tid & 63, sub = tid >> 6;
  for (int idx = tid; idx < D * (D / 2); idx += 256) {
    float2 w = load_pair(Wpr, idx, isf);
    Wp[idx >> 6][idx & 63] = pack_bf16x2(w.x, w.y);
  }
  float2 bgv = load_pair(bg, j2, isf);
  float2 bpv = load_pair(bp, j2, isf);
  __syncthreads();

  int blockRow = blockIdx.x * ROWS_PER_BLOCK;
  for (int r = sub; r < ROWS_PER_BLOCK; r += 4) {
    int node = blockRow + r;
    if (node >= n_prot) break;
    int s0 = offsets[node], s1 = offsets[node + 1];
    float dn = dinv[node];
    float ic = invcnt[node];
    float accx = 0.f, accy = 0.f;
#pragma unroll 2
    for (int k = s0; k < s1; ++k) {
      uint entry = csr[k];
      uint src = entry & 0x7fffffffu;
      const uint* rowp = (entry & 0x80000000u) ? (yd2 + (size_t)src * 64)
                                               : (xw2 + (size_t)src * 64);
      float c = (entry & 0x80000000u) ? ic : dinv[src] * dn;
      float2 v = bf16x2(rowp[j2]);
      accx = fmaf(v.x, c, accx);
      accy = fmaf(v.y, c, accy);
    }
    // self-loop
    float2 xwv = bf16x2(xw2[(size_t)node * 64 + j2]);
    float sc = dn * dn;
    // x3 = x_prot[node] @ W_pr
    float2 xv = load_pair(X, (size_t)node * 64 + j2, isf);
    float ax = 0.f, ay = 0.f;
#pragma unroll 16
    for (int kk = 0; kk < 64; ++kk) {
      float xa = __shfl(xv.x, kk);
      float xb = __shfl(xv.y, kk);
      float2 w0 = bf16x2(Wp[2 * kk][j2]);
      float2 w1 = bf16x2(Wp[2 * kk + 1][j2]);
      ax = fmaf(xa, w0.x, fmaf(xb, w1.x, ax));
      ay = fmaf(xa, w0.y, fmaf(xb, w1.y, ay));
    }
    float v0 = accx + xwv.x * sc + ax + bpv.x + bgv.x + 1e-6f;
    float v1 = accy + xwv.y * sc + ay + bpv.y + bgv.y + 1e-6f;
    float s = v0 + v1, ss = v0 * v0 + v1 * v1;
    for (int off = 1; off < 64; off <<= 1) {
      s += __shfl_xor(s, off);
      ss += __shfl_xor(ss, off);
    }
    float mu = s * (1.0f / 128.0f);
    float var = ss * (1.0f / 128.0f) - mu * mu;
    float rs = rsqrtf(var + 1e-5f);
    float o0 = (v0 - mu) * rs, o1 = (v1 - mu) * rs;
    if (isf)
      ((float2*)out)[(size_t)node * 64 + j2] = make_float2(o0, o1);
    else
      ((uint*)out)[(size_t)node * 64 + j2] = pack_bf16x2(o0, o1);
  }
}

// ---------------------------------------------------------------------------
extern "C" void kernel_launch(void* const* d_in, const int* in_sizes, int n_in,
                              void* d_out, int out_size, void* d_ws,
                              size_t ws_size, hipStream_t stream) {
  const void* x_prot = d_in[0];
  const void* x_drug = d_in[1];
  const void* W_gcn = d_in[2];
  const void* b_gcn = d_in[3];
  const void* W_td = d_in[4];
  const void* b_td = d_in[5];
  const void* W_pr = d_in[6];
  const void* b_pr = d_in[7];
  const int* ppi = (const int*)d_in[8];
  const int* dti_drug = (const int*)d_in[9];
  const int* dti_prot = (const int*)d_in[10];

  int n_prot = in_sizes[0] / D;
  int n_drug = in_sizes[1] / D;
  int e_ppi = in_sizes[8] / 2;
  int e_dti = in_sizes[9];
  int e_tot = e_ppi + e_dti;
  int nb = (n_prot + 255) / 256;

  char* ws = (char*)d_ws;
  size_t off = 0;
  auto alloc = [&](size_t bytes) {
    void* p = ws + off;
    off = (off + bytes + 255) & ~(size_t)255;
    return p;
  };
  int* flag = (int*)alloc(256);
  uint* xw2 = (uint*)alloc((size_t)n_prot * 64 * 4);   // 25.6 MB
  uint* yd2 = (uint*)alloc((size_t)n_drug * 64 * 4);   //  5.1 MB
  int* deg = (int*)alloc((size_t)n_prot * 4);
  int* cnt = (int*)alloc((size_t)n_prot * 4);
  float* dinv = (float*)alloc((size_t)n_prot * 4);
  float* invcnt = (float*)alloc((size_t)n_prot * 4);
  int* tot = (int*)alloc((size_t)n_prot * 4);
  int* offsets = (int*)alloc((size_t)(n_prot + 1) * 4);
  int* fpos = (int*)alloc((size_t)n_prot * 4);
  int* bsum = (int*)alloc((size_t)nb * 4);
  uint* csr = (uint*)alloc((size_t)e_tot * 4);         //  9.6 MB

  if (off > ws_size) return;  // insufficient workspace: bail cleanly

  detect_kernel<<<1, 256, 0, stream>>>((const uint*)x_prot, 4096, flag);

  hipMemsetAsync(deg, 0, (size_t)n_prot * 4, stream);
  hipMemsetAsync(cnt, 0, (size_t)n_prot * 4, stream);
  hipMemsetAsync(fpos, 0, (size_t)n_prot * 4, stream);

  count_kernel<<<(e_tot + 255) / 256, 256, 0, stream>>>(
      ppi + e_ppi, dti_prot, deg, cnt, e_ppi, e_dti, n_prot);
  dinv_kernel<<<nb, 256, 0, stream>>>(deg, cnt, dinv, invcnt, tot, n_prot);

  block_sum_kernel<<<nb, 256, 0, stream>>>(tot, n_prot, bsum);
  scan_bsums_kernel<<<1, 1024, 0, stream>>>(bsum, nb);
  scan_final_kernel<<<nb, 256, 0, stream>>>(tot, bsum, offsets, n_prot);

  fill_kernel<<<(e_tot + 255) / 256, 256, 0, stream>>>(
      ppi, ppi + e_ppi, dti_drug, dti_prot, offsets, fpos, csr, e_ppi, e_dti,
      n_prot);

  int gblocks_p = (n_prot + ROWS_PER_BLOCK - 1) / ROWS_PER_BLOCK;
  int gblocks_d = (n_drug + ROWS_PER_BLOCK - 1) / ROWS_PER_BLOCK;
  gemm_kernel<<<gblocks_p, 256, 0, stream>>>(x_prot, W_gcn, nullptr, xw2, flag,
                                             n_prot);
  gemm_kernel<<<gblocks_d, 256, 0, stream>>>(x_drug, W_td, b_td, yd2, flag,
                                             n_drug);

  gather_ln_kernel<<<gblocks_p, 256, 0, stream>>>(
      x_prot, W_pr, xw2, yd2, dinv, invcnt, offsets, csr, b_gcn, b_pr, d_out,
      flag, n_prot);
}

// Round 5
// 883.125 us; speedup vs baseline: 3.2048x; 1.3474x over previous
//
#include <hip/hip_runtime.h>
#include <hip/hip_bf16.h>

#define D 128
#define NODES_PER_BLOCK 64

typedef unsigned int uint;

// unpack a bf16x2 (as uint) into two floats: x = low half, y = high half
static __device__ __forceinline__ float2 bf16x2(uint u) {
  float2 r;
  r.x = __uint_as_float(u << 16);
  r.y = __uint_as_float(u & 0xffff0000u);
  return r;
}

static __device__ __forceinline__ uint pack_bf16x2(float a, float b) {
  __hip_bfloat162 o;
  o.x = __float2bfloat16(a);
  o.y = __float2bfloat16(b);
  return *reinterpret_cast<uint*>(&o);
}

// load element-pair idx from a float matrix stored fp32 (isf=1) or bf16 (isf=0)
static __device__ __forceinline__ float2 load_pair(const void* X, size_t idx,
                                                   int isf) {
  if (isf) return ((const float2*)X)[idx];
  return bf16x2(((const uint*)X)[idx]);
}

// ---------------------------------------------------------------------------
// Detect input dtype (bf16 vs fp32 storage). flag=1 means fp32.
// ---------------------------------------------------------------------------
__global__ void detect_kernel(const uint* __restrict__ x, int n_words,
                              int* __restrict__ flag) {
  __shared__ float smax[256];
  float m = 0.f;
  for (int i = threadIdx.x; i < n_words; i += 256) {
    float2 v = bf16x2(x[i]);
    float a = fabsf(v.x), b = fabsf(v.y);
    if (!(a <= 1e30f)) a = 1e30f;
    if (!(b <= 1e30f)) b = 1e30f;
    m = fmaxf(m, fmaxf(a, b));
  }
  smax[threadIdx.x] = m;
  __syncthreads();
  for (int s = 128; s > 0; s >>= 1) {
    if (threadIdx.x < s)
      smax[threadIdx.x] = fmaxf(smax[threadIdx.x], smax[threadIdx.x + s]);
    __syncthreads();
  }
  if (threadIdx.x == 0) *flag = (smax[0] > 1e6f) ? 1 : 0;
}

// ---------------------------------------------------------------------------
// Histogram of edge destinations: deg (PPI col), cnt (DTI prot)
// ---------------------------------------------------------------------------
__global__ void count_kernel(const int* __restrict__ ppi_col,
                             const int* __restrict__ dti_prot,
                             int* __restrict__ deg, int* __restrict__ cnt,
                             int e_ppi, int e_dti, int n_prot) {
  int i = blockIdx.x * blockDim.x + threadIdx.x;
  if (i < e_ppi) {
    int c = ppi_col[i];
    if ((unsigned)c < (unsigned)n_prot) atomicAdd(&deg[c], 1);
  } else if (i < e_ppi + e_dti) {
    int c = dti_prot[i - e_ppi];
    if ((unsigned)c < (unsigned)n_prot) atomicAdd(&cnt[c], 1);
  }
}

__global__ void dinv_kernel(const int* __restrict__ deg,
                            const int* __restrict__ cnt,
                            float* __restrict__ dinv,
                            float* __restrict__ invcnt,
                            int* __restrict__ tot, int n) {
  int i = blockIdx.x * blockDim.x + threadIdx.x;
  if (i < n) {
    dinv[i] = rsqrtf((float)(deg[i] + 1));  // +1 self-loop
    invcnt[i] = 1.0f / fmaxf((float)cnt[i], 1.0f);
    tot[i] = deg[i] + cnt[i];
  }
}

// ---------------------------------------------------------------------------
// Exclusive scan of tot -> offsets (3-kernel scheme)
// ---------------------------------------------------------------------------
__global__ void block_sum_kernel(const int* __restrict__ tot, int n,
                                 int* __restrict__ bsum) {
  __shared__ int sh[256];
  int i = blockIdx.x * 256 + threadIdx.x;
  sh[threadIdx.x] = (i < n) ? tot[i] : 0;
  __syncthreads();
  for (int s = 128; s > 0; s >>= 1) {
    if (threadIdx.x < s) sh[threadIdx.x] += sh[threadIdx.x + s];
    __syncthreads();
  }
  if (threadIdx.x == 0) bsum[blockIdx.x] = sh[0];
}

// single block: in-place exclusive scan of bsum[0..nb)
__global__ void scan_bsums_kernel(int* __restrict__ bsum, int nb) {
  __shared__ int sh[1024];
  __shared__ int carry;
  int tid = threadIdx.x;
  if (tid == 0) carry = 0;
  __syncthreads();
  for (int base = 0; base < nb; base += 1024) {
    int i = base + tid;
    int v = (i < nb) ? bsum[i] : 0;
    sh[tid] = v;
    __syncthreads();
    for (int ofs = 1; ofs < 1024; ofs <<= 1) {
      int t = (tid >= ofs) ? sh[tid - ofs] : 0;
      __syncthreads();
      sh[tid] += t;
      __syncthreads();
    }
    if (i < nb) bsum[i] = carry + sh[tid] - v;  // exclusive
    int total = sh[1023];
    __syncthreads();
    if (tid == 0) carry += total;
    __syncthreads();
  }
}

__global__ void scan_final_kernel(const int* __restrict__ tot,
                                  const int* __restrict__ bbase,
                                  int* __restrict__ offsets, int n) {
  __shared__ int sh[256];
  int tid = threadIdx.x;
  int i = blockIdx.x * 256 + tid;
  int v = (i < n) ? tot[i] : 0;
  sh[tid] = v;
  __syncthreads();
  for (int ofs = 1; ofs < 256; ofs <<= 1) {
    int t = (tid >= ofs) ? sh[tid - ofs] : 0;
    __syncthreads();
    sh[tid] += t;
    __syncthreads();
  }
  if (i < n) {
    int excl = bbase[blockIdx.x] + sh[tid] - v;
    offsets[i] = excl;
    if (i == n - 1) offsets[n] = excl + v;
  }
}

// ---------------------------------------------------------------------------
// Fill CSR, segmented per node: [offsets[d], offsets[d]+deg[d]) = PPI sources,
// [offsets[d]+deg[d], offsets[d+1]) = DTI drug sources.
// ---------------------------------------------------------------------------
__global__ void fill_kernel(const int* __restrict__ ppi_row,
                            const int* __restrict__ ppi_col,
                            const int* __restrict__ dti_drug,
                            const int* __restrict__ dti_prot,
                            const int* __restrict__ offsets,
                            const int* __restrict__ deg,
                            int* __restrict__ fposp, int* __restrict__ fposd,
                            uint* __restrict__ csr, int e_ppi, int e_dti,
                            int n_prot) {
  int i = blockIdx.x * blockDim.x + threadIdx.x;
  if (i < e_ppi) {
    int dst = ppi_col[i];
    if ((unsigned)dst >= (unsigned)n_prot) return;
    int pos = offsets[dst] + atomicAdd(&fposp[dst], 1);
    csr[pos] = (uint)ppi_row[i];
  } else if (i < e_ppi + e_dti) {
    int j = i - e_ppi;
    int dst = dti_prot[j];
    if ((unsigned)dst >= (unsigned)n_prot) return;
    int pos = offsets[dst] + deg[dst] + atomicAdd(&fposd[dst], 1);
    csr[pos] = (uint)dti_drug[j];
  }
}

// ---------------------------------------------------------------------------
// Y2[M][64] (packed bf16 pairs) = (X[M,128] @ W[128,128] + bias) * rowscale.
// 512 threads = 8 waves; W in LDS as uint2 (bf16x2 pairs for k=2kk,2kk+1);
// each wave does 2 rows per iteration (shuffle-broadcast of X row).
// ---------------------------------------------------------------------------
__global__ __launch_bounds__(512) void gemm_kernel(
    const void* __restrict__ X, const void* __restrict__ W,
    const void* __restrict__ bias, const float* __restrict__ rowscale,
    uint* __restrict__ Y2, const int* __restrict__ flag, int M) {
  __shared__ uint2 Wp2[64][64];  // 32 KB packed bf16
  int isf = *flag;
  int tid = threadIdx.x;
  int j2 = tid & 63, sub = tid >> 6;
  for (int idx = tid; idx < 64 * 64; idx += 512) {
    int kk = idx >> 6, j = idx & 63;
    float2 wa = load_pair(W, (size_t)(2 * kk) * 64 + j, isf);
    float2 wb = load_pair(W, (size_t)(2 * kk + 1) * 64 + j, isf);
    Wp2[kk][j] = make_uint2(pack_bf16x2(wa.x, wa.y), pack_bf16x2(wb.x, wb.y));
  }
  float2 b = make_float2(0.f, 0.f);
  if (bias) b = load_pair(bias, j2, isf);
  __syncthreads();

  int blockRow = blockIdx.x * NODES_PER_BLOCK;
  for (int r = 2 * sub; r < NODES_PER_BLOCK; r += 16) {
    int r0 = blockRow + r, r1 = r0 + 1;
    if (r0 >= M) break;
    bool has1 = (r1 < M);
    float2 xv0 = load_pair(X, (size_t)r0 * 64 + j2, isf);
    float2 xv1 = has1 ? load_pair(X, (size_t)r1 * 64 + j2, isf)
                      : make_float2(0.f, 0.f);
    float ax0 = 0.f, ay0 = 0.f, ax1 = 0.f, ay1 = 0.f;
#pragma unroll 8
    for (int kk = 0; kk < 64; ++kk) {
      uint2 w = Wp2[kk][j2];
      float2 w0 = bf16x2(w.x), w1 = bf16x2(w.y);
      float xa0 = __shfl(xv0.x, kk), xb0 = __shfl(xv0.y, kk);
      float xa1 = __shfl(xv1.x, kk), xb1 = __shfl(xv1.y, kk);
      ax0 = fmaf(xa0, w0.x, fmaf(xb0, w1.x, ax0));
      ay0 = fmaf(xa0, w0.y, fmaf(xb0, w1.y, ay0));
      ax1 = fmaf(xa1, w0.x, fmaf(xb1, w1.x, ax1));
      ay1 = fmaf(xa1, w0.y, fmaf(xb1, w1.y, ay1));
    }
    float s0 = rowscale ? rowscale[r0] : 1.f;
    Y2[(size_t)r0 * 64 + j2] = pack_bf16x2((ax0 + b.x) * s0, (ay0 + b.y) * s0);
    if (has1) {
      float s1 = rowscale ? rowscale[r1] : 1.f;
      Y2[(size_t)r1 * 64 + j2] =
          pack_bf16x2((ax1 + b.x) * s1, (ay1 + b.y) * s1);
    }
  }
}

// ---------------------------------------------------------------------------
// Fused gather + x3-GEMM + LayerNorm. One wave per node.
// xw2 rows are PRE-SCALED by dinv[src], so:
//   x1[node] = dn * (sum_ppi xw2[src]) + dn * xw2[node]   (self-loop)
//   x2[node] = ic * (sum_dti yd2[drug])
// CSR entries for a node are lane-cooperatively loaded then shfl-broadcast;
// row gathers are independent (4-wide batches) for load pipelining.
// ---------------------------------------------------------------------------
__global__ __launch_bounds__(512) void gather_ln_kernel(
    const void* __restrict__ X, const void* __restrict__ Wpr,
    const uint* __restrict__ xw2, const uint* __restrict__ yd2,
    const float* __restrict__ dinv, const float* __restrict__ invcnt,
    const int* __restrict__ offsets, const int* __restrict__ deg,
    const uint* __restrict__ csr, const void* __restrict__ bg,
    const void* __restrict__ bp, void* __restrict__ out,
    const int* __restrict__ flag, int n_prot) {
  __shared__ uint2 Wp2[64][64];  // 32 KB packed bf16
  int isf = *flag;
  int tid = threadIdx.x;
  int j2 = tid & 63, sub = tid >> 6;
  for (int idx = tid; idx < 64 * 64; idx += 512) {
    int kk = idx >> 6, j = idx & 63;
    float2 wa = load_pair(Wpr, (size_t)(2 * kk) * 64 + j, isf);
    float2 wb = load_pair(Wpr, (size_t)(2 * kk + 1) * 64 + j, isf);
    Wp2[kk][j] = make_uint2(pack_bf16x2(wa.x, wa.y), pack_bf16x2(wb.x, wb.y));
  }
  float2 bgv = load_pair(bg, j2, isf);
  float2 bpv = load_pair(bp, j2, isf);
  __syncthreads();

  int blockBase = blockIdx.x * NODES_PER_BLOCK;
  for (int r = sub; r < NODES_PER_BLOCK; r += 8) {
    int node = blockBase + r;
    if (node >= n_prot) break;
    int s0 = offsets[node];
    int s1 = offsets[node + 1];
    int sm = s0 + deg[node];
    float dn = dinv[node];
    float ic = invcnt[node];

    float apx = 0.f, apy = 0.f;  // PPI sum (of pre-scaled rows)
    // --- PPI segment ---
    for (int base = s0; base < sm;) {
      int m = min(64, sm - base);
      uint ent = (j2 < m) ? csr[base + j2] : 0u;
      int j = 0;
      for (; j + 4 <= m; j += 4) {
        uint e0 = __shfl(ent, j), e1 = __shfl(ent, j + 1);
        uint e2 = __shfl(ent, j + 2), e3 = __shfl(ent, j + 3);
        float2 v0 = bf16x2(xw2[(size_t)e0 * 64 + j2]);
        float2 v1 = bf16x2(xw2[(size_t)e1 * 64 + j2]);
        float2 v2 = bf16x2(xw2[(size_t)e2 * 64 + j2]);
        float2 v3 = bf16x2(xw2[(size_t)e3 * 64 + j2]);
        apx += (v0.x + v1.x) + (v2.x + v3.x);
        apy += (v0.y + v1.y) + (v2.y + v3.y);
      }
      for (; j < m; ++j) {
        uint e = __shfl(ent, j);
        float2 v = bf16x2(xw2[(size_t)e * 64 + j2]);
        apx += v.x;
        apy += v.y;
      }
      base += m;
    }
    // --- DTI segment ---
    float adx = 0.f, ady = 0.f;
    for (int base = sm; base < s1;) {
      int m = min(64, s1 - base);
      uint ent = (j2 < m) ? csr[base + j2] : 0u;
      int j = 0;
      for (; j + 4 <= m; j += 4) {
        uint e0 = __shfl(ent, j), e1 = __shfl(ent, j + 1);
        uint e2 = __shfl(ent, j + 2), e3 = __shfl(ent, j + 3);
        float2 v0 = bf16x2(yd2[(size_t)e0 * 64 + j2]);
        float2 v1 = bf16x2(yd2[(size_t)e1 * 64 + j2]);
        float2 v2 = bf16x2(yd2[(size_t)e2 * 64 + j2]);
        float2 v3 = bf16x2(yd2[(size_t)e3 * 64 + j2]);
        adx += (v0.x + v1.x) + (v2.x + v3.x);
        ady += (v0.y + v1.y) + (v2.y + v3.y);
      }
      for (; j < m; ++j) {
        uint e = __shfl(ent, j);
        float2 v = bf16x2(yd2[(size_t)e * 64 + j2]);
        adx += v.x;
        ady += v.y;
      }
      base += m;
    }

    // --- x3 = x_prot[node] @ W_pr (shuffle GEMM over LDS W) ---
    float2 xv = load_pair(X, (size_t)node * 64 + j2, isf);
    float ax = 0.f, ay = 0.f;
#pragma unroll 8
    for (int kk = 0; kk < 64; ++kk) {
      uint2 w = Wp2[kk][j2];
      float2 w0 = bf16x2(w.x), w1 = bf16x2(w.y);
      float xa = __shfl(xv.x, kk), xb = __shfl(xv.y, kk);
      ax = fmaf(xa, w0.x, fmaf(xb, w1.x, ax));
      ay = fmaf(xa, w0.y, fmaf(xb, w1.y, ay));
    }

    // self-loop (xw2 is pre-scaled by dinv[node])
    float2 xwv = bf16x2(xw2[(size_t)node * 64 + j2]);
    float v0 = fmaf(apx + xwv.x, dn, fmaf(adx, ic, ax)) + bpv.x + bgv.x + 1e-6f;
    float v1 = fmaf(apy + xwv.y, dn, fmaf(ady, ic, ay)) + bpv.y + bgv.y + 1e-6f;

    float s = v0 + v1, ss = v0 * v0 + v1 * v1;
    for (int off = 1; off < 64; off <<= 1) {
      s += __shfl_xor(s, off);
      ss += __shfl_xor(ss, off);
    }
    float mu = s * (1.0f / 128.0f);
    float var = ss * (1.0f / 128.0f) - mu * mu;
    float rs = rsqrtf(var + 1e-5f);
    float o0 = (v0 - mu) * rs, o1 = (v1 - mu) * rs;
    if (isf)
      ((float2*)out)[(size_t)node * 64 + j2] = make_float2(o0, o1);
    else
      ((uint*)out)[(size_t)node * 64 + j2] = pack_bf16x2(o0, o1);
  }
}

// ---------------------------------------------------------------------------
extern "C" void kernel_launch(void* const* d_in, const int* in_sizes, int n_in,
                              void* d_out, int out_size, void* d_ws,
                              size_t ws_size, hipStream_t stream) {
  const void* x_prot = d_in[0];
  const void* x_drug = d_in[1];
  const void* W_gcn = d_in[2];
  const void* b_gcn = d_in[3];
  const void* W_td = d_in[4];
  const void* b_td = d_in[5];
  const void* W_pr = d_in[6];
  const void* b_pr = d_in[7];
  const int* ppi = (const int*)d_in[8];
  const int* dti_drug = (const int*)d_in[9];
  const int* dti_prot = (const int*)d_in[10];

  int n_prot = in_sizes[0] / D;
  int n_drug = in_sizes[1] / D;
  int e_ppi = in_sizes[8] / 2;
  int e_dti = in_sizes[9];
  int e_tot = e_ppi + e_dti;
  int nb = (n_prot + 255) / 256;

  char* ws = (char*)d_ws;
  size_t off = 0;
  auto alloc = [&](size_t bytes) {
    void* p = ws + off;
    off = (off + bytes + 255) & ~(size_t)255;
    return p;
  };
  int* flag = (int*)alloc(256);
  uint* xw2 = (uint*)alloc((size_t)n_prot * 64 * 4);  // 25.6 MB (pre-scaled)
  uint* yd2 = (uint*)alloc((size_t)n_drug * 64 * 4);  //  5.1 MB
  int* deg = (int*)alloc((size_t)n_prot * 4);
  int* cnt = (int*)alloc((size_t)n_prot * 4);
  float* dinv = (float*)alloc((size_t)n_prot * 4);
  float* invcnt = (float*)alloc((size_t)n_prot * 4);
  int* tot = (int*)alloc((size_t)n_prot * 4);
  int* offsets = (int*)alloc((size_t)(n_prot + 1) * 4);
  int* fposp = (int*)alloc((size_t)n_prot * 4);
  int* fposd = (int*)alloc((size_t)n_prot * 4);
  int* bsum = (int*)alloc((size_t)nb * 4);
  uint* csr = (uint*)alloc((size_t)e_tot * 4);  // 9.6 MB

  if (off > ws_size) return;  // insufficient workspace: bail cleanly

  detect_kernel<<<1, 256, 0, stream>>>((const uint*)x_prot, 4096, flag);

  hipMemsetAsync(deg, 0, (size_t)n_prot * 4, stream);
  hipMemsetAsync(cnt, 0, (size_t)n_prot * 4, stream);
  hipMemsetAsync(fposp, 0, (size_t)n_prot * 4, stream);
  hipMemsetAsync(fposd, 0, (size_t)n_prot * 4, stream);

  count_kernel<<<(e_tot + 255) / 256, 256, 0, stream>>>(
      ppi + e_ppi, dti_prot, deg, cnt, e_ppi, e_dti, n_prot);
  dinv_kernel<<<nb, 256, 0, stream>>>(deg, cnt, dinv, invcnt, tot, n_prot);

  block_sum_kernel<<<nb, 256, 0, stream>>>(tot, n_prot, bsum);
  scan_bsums_kernel<<<1, 1024, 0, stream>>>(bsum, nb);
  scan_final_kernel<<<nb, 256, 0, stream>>>(tot, bsum, offsets, n_prot);

  fill_kernel<<<(e_tot + 255) / 256, 256, 0, stream>>>(
      ppi, ppi + e_ppi, dti_drug, dti_prot, offsets, deg, fposp, fposd, csr,
      e_ppi, e_dti, n_prot);

  int gblocks_p = (n_prot + NODES_PER_BLOCK - 1) / NODES_PER_BLOCK;
  int gblocks_d = (n_drug + NODES_PER_BLOCK - 1) / NODES_PER_BLOCK;
  gemm_kernel<<<gblocks_p, 512, 0, stream>>>(x_prot, W_gcn, nullptr, dinv, xw2,
                                             flag, n_prot);
  gemm_kernel<<<gblocks_d, 512, 0, stream>>>(x_drug, W_td, b_td, nullptr, yd2,
                                             flag, n_drug);

  gather_ln_kernel<<<gblocks_p, 512, 0, stream>>>(
      x_prot, W_pr, xw2, yd2, dinv, invcnt, offsets, deg, csr, b_gcn, b_pr,
      d_out, flag, n_prot);
}

// Round 6
// 780.914 us; speedup vs baseline: 3.6242x; 1.1309x over previous
//
#include <hip/hip_runtime.h>
#include <hip/hip_bf16.h>

#define D 128
#define NPB 64  // rows per block in GEMM kernels

typedef unsigned int uint;

// unpack a bf16x2 (as uint) into two floats: x = low half, y = high half
static __device__ __forceinline__ float2 bf16x2(uint u) {
  float2 r;
  r.x = __uint_as_float(u << 16);
  r.y = __uint_as_float(u & 0xffff0000u);
  return r;
}

static __device__ __forceinline__ uint pack_bf16x2(float a, float b) {
  __hip_bfloat162 o;
  o.x = __float2bfloat16(a);
  o.y = __float2bfloat16(b);
  return *reinterpret_cast<uint*>(&o);
}

// load element-pair idx from a float matrix stored fp32 (isf=1) or bf16 (isf=0)
static __device__ __forceinline__ float2 load_pair(const void* X, size_t idx,
                                                   int isf) {
  if (isf) return ((const float2*)X)[idx];
  return bf16x2(((const uint*)X)[idx]);
}

// ---------------------------------------------------------------------------
// Detect input dtype (bf16 vs fp32 storage). flag=1 means fp32.
// ---------------------------------------------------------------------------
__global__ void detect_kernel(const uint* __restrict__ x, int n_words,
                              int* __restrict__ flag) {
  __shared__ float smax[256];
  float m = 0.f;
  for (int i = threadIdx.x; i < n_words; i += 256) {
    float2 v = bf16x2(x[i]);
    float a = fabsf(v.x), b = fabsf(v.y);
    if (!(a <= 1e30f)) a = 1e30f;
    if (!(b <= 1e30f)) b = 1e30f;
    m = fmaxf(m, fmaxf(a, b));
  }
  smax[threadIdx.x] = m;
  __syncthreads();
  for (int s = 128; s > 0; s >>= 1) {
    if (threadIdx.x < s)
      smax[threadIdx.x] = fmaxf(smax[threadIdx.x], smax[threadIdx.x + s]);
    __syncthreads();
  }
  if (threadIdx.x == 0) *flag = (smax[0] > 1e6f) ? 1 : 0;
}

// ---------------------------------------------------------------------------
// Histogram of edge destinations: deg (PPI col), cnt (DTI prot)
// ---------------------------------------------------------------------------
__global__ void count_kernel(const int* __restrict__ ppi_col,
                             const int* __restrict__ dti_prot,
                             int* __restrict__ deg, int* __restrict__ cnt,
                             int e_ppi, int e_dti, int n_prot) {
  int i = blockIdx.x * blockDim.x + threadIdx.x;
  if (i < e_ppi) {
    int c = ppi_col[i];
    if ((unsigned)c < (unsigned)n_prot) atomicAdd(&deg[c], 1);
  } else if (i < e_ppi + e_dti) {
    int c = dti_prot[i - e_ppi];
    if ((unsigned)c < (unsigned)n_prot) atomicAdd(&cnt[c], 1);
  }
}

// ---------------------------------------------------------------------------
// Per-node normalizers + per-scan-block sums (fused)
// ---------------------------------------------------------------------------
__global__ void block_sum_kernel(const int* __restrict__ deg,
                                 const int* __restrict__ cnt, int n,
                                 float* __restrict__ dinv,
                                 float* __restrict__ invcnt,
                                 int* __restrict__ bsum) {
  __shared__ int sh[256];
  int i = blockIdx.x * 256 + threadIdx.x;
  int t = 0;
  if (i < n) {
    int d = deg[i], c = cnt[i];
    dinv[i] = rsqrtf((float)(d + 1));  // +1 self-loop
    invcnt[i] = 1.0f / fmaxf((float)c, 1.0f);
    t = d + c;
  }
  sh[threadIdx.x] = t;
  __syncthreads();
  for (int s = 128; s > 0; s >>= 1) {
    if (threadIdx.x < s) sh[threadIdx.x] += sh[threadIdx.x + s];
    __syncthreads();
  }
  if (threadIdx.x == 0) bsum[blockIdx.x] = sh[0];
}

// single block: in-place exclusive scan of bsum[0..nb)
__global__ void scan_bsums_kernel(int* __restrict__ bsum, int nb) {
  __shared__ int sh[1024];
  __shared__ int carry;
  int tid = threadIdx.x;
  if (tid == 0) carry = 0;
  __syncthreads();
  for (int base = 0; base < nb; base += 1024) {
    int i = base + tid;
    int v = (i < nb) ? bsum[i] : 0;
    sh[tid] = v;
    __syncthreads();
    for (int ofs = 1; ofs < 1024; ofs <<= 1) {
      int t = (tid >= ofs) ? sh[tid - ofs] : 0;
      __syncthreads();
      sh[tid] += t;
      __syncthreads();
    }
    if (i < nb) bsum[i] = carry + sh[tid] - v;  // exclusive
    int total = sh[1023];
    __syncthreads();
    if (tid == 0) carry += total;
    __syncthreads();
  }
}

__global__ void scan_final_kernel(const int* __restrict__ deg,
                                  const int* __restrict__ cnt,
                                  const int* __restrict__ bbase,
                                  int* __restrict__ offsets, int n) {
  __shared__ int sh[256];
  int tid = threadIdx.x;
  int i = blockIdx.x * 256 + tid;
  int v = (i < n) ? deg[i] + cnt[i] : 0;
  sh[tid] = v;
  __syncthreads();
  for (int ofs = 1; ofs < 256; ofs <<= 1) {
    int t = (tid >= ofs) ? sh[tid - ofs] : 0;
    __syncthreads();
    sh[tid] += t;
    __syncthreads();
  }
  if (i < n) {
    int excl = bbase[blockIdx.x] + sh[tid] - v;
    offsets[i] = excl;
    if (i == n - 1) offsets[n] = excl + v;
  }
}

// ---------------------------------------------------------------------------
// Fill CSR, segmented per node: [offsets[d], offsets[d]+deg[d]) = PPI sources,
// [offsets[d]+deg[d], offsets[d+1]) = DTI drug sources.
// ---------------------------------------------------------------------------
__global__ void fill_kernel(const int* __restrict__ ppi_row,
                            const int* __restrict__ ppi_col,
                            const int* __restrict__ dti_drug,
                            const int* __restrict__ dti_prot,
                            const int* __restrict__ offsets,
                            const int* __restrict__ deg,
                            int* __restrict__ fposp, int* __restrict__ fposd,
                            uint* __restrict__ csr, int e_ppi, int e_dti,
                            int n_prot) {
  int i = blockIdx.x * blockDim.x + threadIdx.x;
  if (i < e_ppi) {
    int dst = ppi_col[i];
    if ((unsigned)dst >= (unsigned)n_prot) return;
    int pos = offsets[dst] + atomicAdd(&fposp[dst], 1);
    csr[pos] = (uint)ppi_row[i];
  } else if (i < e_ppi + e_dti) {
    int j = i - e_ppi;
    int dst = dti_prot[j];
    if ((unsigned)dst >= (unsigned)n_prot) return;
    int pos = offsets[dst] + deg[dst] + atomicAdd(&fposd[dst], 1);
    csr[pos] = (uint)dti_drug[j];
  }
}

// ---------------------------------------------------------------------------
// Dual-output protein GEMM over shared X rows:
//   g = x_prot[row] @ W_gcn
//   xw2[row]  = bf16(g * dinv[row])                          (gather source)
//   x3'[row]  = x_prot[row] @ W_pr + (b_pr+b_gcn+1e-6) + dinv^2 * g
//               -> stored INTO d_out in the output dtype (self-loop folded)
// 512 threads = 8 waves; both W's packed bf16 in LDS (64 KB total).
// ---------------------------------------------------------------------------
__global__ __launch_bounds__(512) void gemm_prot_kernel(
    const void* __restrict__ X, const void* __restrict__ Wg,
    const void* __restrict__ Wp, const void* __restrict__ bg,
    const void* __restrict__ bp, const float* __restrict__ dinv,
    uint* __restrict__ xw2, void* __restrict__ outx3,
    const int* __restrict__ flag, int M) {
  __shared__ uint2 Wg2[64][64];  // 32 KB
  __shared__ uint2 Wp2[64][64];  // 32 KB
  int isf = *flag;
  int tid = threadIdx.x;
  int j2 = tid & 63, sub = tid >> 6;
  for (int idx = tid; idx < 64 * 64; idx += 512) {
    int kk = idx >> 6, j = idx & 63;
    float2 a = load_pair(Wg, (size_t)(2 * kk) * 64 + j, isf);
    float2 b = load_pair(Wg, (size_t)(2 * kk + 1) * 64 + j, isf);
    Wg2[kk][j] = make_uint2(pack_bf16x2(a.x, a.y), pack_bf16x2(b.x, b.y));
    a = load_pair(Wp, (size_t)(2 * kk) * 64 + j, isf);
    b = load_pair(Wp, (size_t)(2 * kk + 1) * 64 + j, isf);
    Wp2[kk][j] = make_uint2(pack_bf16x2(a.x, a.y), pack_bf16x2(b.x, b.y));
  }
  float2 bgv = load_pair(bg, j2, isf);
  float2 bpv = load_pair(bp, j2, isf);
  float btx = bgv.x + bpv.x + 1e-6f, bty = bgv.y + bpv.y + 1e-6f;
  __syncthreads();

  int blockRow = blockIdx.x * NPB;
  for (int r = sub; r < NPB; r += 8) {
    int row = blockRow + r;
    if (row >= M) break;
    float2 xv = load_pair(X, (size_t)row * 64 + j2, isf);
    float gx = 0.f, gy = 0.f, px = 0.f, py = 0.f;
#pragma unroll 8
    for (int kk = 0; kk < 64; ++kk) {
      float xa = __shfl(xv.x, kk), xb = __shfl(xv.y, kk);
      uint2 wg = Wg2[kk][j2];
      uint2 wp = Wp2[kk][j2];
      float2 g0 = bf16x2(wg.x), g1 = bf16x2(wg.y);
      float2 p0 = bf16x2(wp.x), p1 = bf16x2(wp.y);
      gx = fmaf(xa, g0.x, fmaf(xb, g1.x, gx));
      gy = fmaf(xa, g0.y, fmaf(xb, g1.y, gy));
      px = fmaf(xa, p0.x, fmaf(xb, p1.x, px));
      py = fmaf(xa, p0.y, fmaf(xb, p1.y, py));
    }
    float dn = dinv[row];
    xw2[(size_t)row * 64 + j2] = pack_bf16x2(gx * dn, gy * dn);
    float sc = dn * dn;
    float ox = fmaf(gx, sc, px + btx);
    float oy = fmaf(gy, sc, py + bty);
    if (isf)
      ((float2*)outx3)[(size_t)row * 64 + j2] = make_float2(ox, oy);
    else
      ((uint*)outx3)[(size_t)row * 64 + j2] = pack_bf16x2(ox, oy);
  }
}

// ---------------------------------------------------------------------------
// Drug GEMM: yd2[M][64] bf16 pairs = x_drug @ W_td + b_td
// ---------------------------------------------------------------------------
__global__ __launch_bounds__(512) void gemm_drug_kernel(
    const void* __restrict__ X, const void* __restrict__ W,
    const void* __restrict__ bias, uint* __restrict__ Y2,
    const int* __restrict__ flag, int M) {
  __shared__ uint2 Wp2[64][64];  // 32 KB
  int isf = *flag;
  int tid = threadIdx.x;
  int j2 = tid & 63, sub = tid >> 6;
  for (int idx = tid; idx < 64 * 64; idx += 512) {
    int kk = idx >> 6, j = idx & 63;
    float2 wa = load_pair(W, (size_t)(2 * kk) * 64 + j, isf);
    float2 wb = load_pair(W, (size_t)(2 * kk + 1) * 64 + j, isf);
    Wp2[kk][j] = make_uint2(pack_bf16x2(wa.x, wa.y), pack_bf16x2(wb.x, wb.y));
  }
  float2 b = load_pair(bias, j2, isf);
  __syncthreads();

  int blockRow = blockIdx.x * NPB;
  for (int r = 2 * sub; r < NPB; r += 16) {
    int r0 = blockRow + r, r1 = r0 + 1;
    if (r0 >= M) break;
    bool has1 = (r1 < M);
    float2 xv0 = load_pair(X, (size_t)r0 * 64 + j2, isf);
    float2 xv1 =
        has1 ? load_pair(X, (size_t)r1 * 64 + j2, isf) : make_float2(0.f, 0.f);
    float ax0 = 0.f, ay0 = 0.f, ax1 = 0.f, ay1 = 0.f;
#pragma unroll 8
    for (int kk = 0; kk < 64; ++kk) {
      uint2 w = Wp2[kk][j2];
      float2 w0 = bf16x2(w.x), w1 = bf16x2(w.y);
      float xa0 = __shfl(xv0.x, kk), xb0 = __shfl(xv0.y, kk);
      float xa1 = __shfl(xv1.x, kk), xb1 = __shfl(xv1.y, kk);
      ax0 = fmaf(xa0, w0.x, fmaf(xb0, w1.x, ax0));
      ay0 = fmaf(xa0, w0.y, fmaf(xb0, w1.y, ay0));
      ax1 = fmaf(xa1, w0.x, fmaf(xb1, w1.x, ax1));
      ay1 = fmaf(xa1, w0.y, fmaf(xb1, w1.y, ay1));
    }
    Y2[(size_t)r0 * 64 + j2] = pack_bf16x2(ax0 + b.x, ay0 + b.y);
    if (has1) Y2[(size_t)r1 * 64 + j2] = pack_bf16x2(ax1 + b.x, ay1 + b.y);
  }
}

// ---------------------------------------------------------------------------
// Pure gather + LayerNorm (no LDS, no GEMM). One wave per node.
//  v = dn * sum_ppi(xw2[src]) + ic * sum_dti(yd2[drug]) + x3'[node]
//  out[node] = LayerNorm(v)   (x3' read from d_out, overwritten in place)
// CSR entries lane-cooperatively loaded + shfl-broadcast; 8-wide batches of
// independent row gathers for memory-level parallelism.
// ---------------------------------------------------------------------------
__global__ __launch_bounds__(256) void gather_ln_kernel(
    const uint* __restrict__ xw2, const uint* __restrict__ yd2,
    const float* __restrict__ dinv, const float* __restrict__ invcnt,
    const int* __restrict__ offsets, const int* __restrict__ deg,
    const uint* __restrict__ csr, void* __restrict__ out,
    const int* __restrict__ flag, int n_prot) {
  int isf = *flag;
  int node = (blockIdx.x * 256 + threadIdx.x) >> 6;
  int j2 = threadIdx.x & 63;
  if (node >= n_prot) return;
  int s0 = offsets[node];
  int s1 = offsets[node + 1];
  int sm = s0 + deg[node];
  float dn = dinv[node], ic = invcnt[node];

  float apx = 0.f, apy = 0.f;  // PPI sum (rows pre-scaled by dinv[src])
  for (int base = s0; base < sm;) {
    int m = min(64, sm - base);
    uint ent = (j2 < m) ? csr[base + j2] : 0u;
    int j = 0;
    for (; j + 8 <= m; j += 8) {
      uint e0 = __shfl(ent, j), e1 = __shfl(ent, j + 1);
      uint e2 = __shfl(ent, j + 2), e3 = __shfl(ent, j + 3);
      uint e4 = __shfl(ent, j + 4), e5 = __shfl(ent, j + 5);
      uint e6 = __shfl(ent, j + 6), e7 = __shfl(ent, j + 7);
      float2 v0 = bf16x2(xw2[(size_t)e0 * 64 + j2]);
      float2 v1 = bf16x2(xw2[(size_t)e1 * 64 + j2]);
      float2 v2 = bf16x2(xw2[(size_t)e2 * 64 + j2]);
      float2 v3 = bf16x2(xw2[(size_t)e3 * 64 + j2]);
      float2 v4 = bf16x2(xw2[(size_t)e4 * 64 + j2]);
      float2 v5 = bf16x2(xw2[(size_t)e5 * 64 + j2]);
      float2 v6 = bf16x2(xw2[(size_t)e6 * 64 + j2]);
      float2 v7 = bf16x2(xw2[(size_t)e7 * 64 + j2]);
      apx += ((v0.x + v1.x) + (v2.x + v3.x)) + ((v4.x + v5.x) + (v6.x + v7.x));
      apy += ((v0.y + v1.y) + (v2.y + v3.y)) + ((v4.y + v5.y) + (v6.y + v7.y));
    }
    for (; j + 2 <= m; j += 2) {
      uint e0 = __shfl(ent, j), e1 = __shfl(ent, j + 1);
      float2 v0 = bf16x2(xw2[(size_t)e0 * 64 + j2]);
      float2 v1 = bf16x2(xw2[(size_t)e1 * 64 + j2]);
      apx += v0.x + v1.x;
      apy += v0.y + v1.y;
    }
    for (; j < m; ++j) {
      uint e = __shfl(ent, j);
      float2 v = bf16x2(xw2[(size_t)e * 64 + j2]);
      apx += v.x;
      apy += v.y;
    }
    base += m;
  }

  float adx = 0.f, ady = 0.f;  // DTI sum
  for (int base = sm; base < s1;) {
    int m = min(64, s1 - base);
    uint ent = (j2 < m) ? csr[base + j2] : 0u;
    int j = 0;
    for (; j + 8 <= m; j += 8) {
      uint e0 = __shfl(ent, j), e1 = __shfl(ent, j + 1);
      uint e2 = __shfl(ent, j + 2), e3 = __shfl(ent, j + 3);
      uint e4 = __shfl(ent, j + 4), e5 = __shfl(ent, j + 5);
      uint e6 = __shfl(ent, j + 6), e7 = __shfl(ent, j + 7);
      float2 v0 = bf16x2(yd2[(size_t)e0 * 64 + j2]);
      float2 v1 = bf16x2(yd2[(size_t)e1 * 64 + j2]);
      float2 v2 = bf16x2(yd2[(size_t)e2 * 64 + j2]);
      float2 v3 = bf16x2(yd2[(size_t)e3 * 64 + j2]);
      float2 v4 = bf16x2(yd2[(size_t)e4 * 64 + j2]);
      float2 v5 = bf16x2(yd2[(size_t)e5 * 64 + j2]);
      float2 v6 = bf16x2(yd2[(size_t)e6 * 64 + j2]);
      float2 v7 = bf16x2(yd2[(size_t)e7 * 64 + j2]);
      adx += ((v0.x + v1.x) + (v2.x + v3.x)) + ((v4.x + v5.x) + (v6.x + v7.x));
      ady += ((v0.y + v1.y) + (v2.y + v3.y)) + ((v4.y + v5.y) + (v6.y + v7.y));
    }
    for (; j + 2 <= m; j += 2) {
      uint e0 = __shfl(ent, j), e1 = __shfl(ent, j + 1);
      float2 v0 = bf16x2(yd2[(size_t)e0 * 64 + j2]);
      float2 v1 = bf16x2(yd2[(size_t)e1 * 64 + j2]);
      adx += v0.x + v1.x;
      ady += v0.y + v1.y;
    }
    for (; j < m; ++j) {
      uint e = __shfl(ent, j);
      float2 v = bf16x2(yd2[(size_t)e * 64 + j2]);
      adx += v.x;
      ady += v.y;
    }
    base += m;
  }

  float2 x3v;
  if (isf)
    x3v = ((const float2*)out)[(size_t)node * 64 + j2];
  else
    x3v = bf16x2(((const uint*)out)[(size_t)node * 64 + j2]);
  float v0 = fmaf(dn, apx, fmaf(ic, adx, x3v.x));
  float v1 = fmaf(dn, apy, fmaf(ic, ady, x3v.y));

  float s = v0 + v1, ss = v0 * v0 + v1 * v1;
  for (int off = 1; off < 64; off <<= 1) {
    s += __shfl_xor(s, off);
    ss += __shfl_xor(ss, off);
  }
  float mu = s * (1.0f / 128.0f);
  float var = ss * (1.0f / 128.0f) - mu * mu;
  float rs = rsqrtf(var + 1e-5f);
  float o0 = (v0 - mu) * rs, o1 = (v1 - mu) * rs;
  if (isf)
    ((float2*)out)[(size_t)node * 64 + j2] = make_float2(o0, o1);
  else
    ((uint*)out)[(size_t)node * 64 + j2] = pack_bf16x2(o0, o1);
}

// ---------------------------------------------------------------------------
extern "C" void kernel_launch(void* const* d_in, const int* in_sizes, int n_in,
                              void* d_out, int out_size, void* d_ws,
                              size_t ws_size, hipStream_t stream) {
  const void* x_prot = d_in[0];
  const void* x_drug = d_in[1];
  const void* W_gcn = d_in[2];
  const void* b_gcn = d_in[3];
  const void* W_td = d_in[4];
  const void* b_td = d_in[5];
  const void* W_pr = d_in[6];
  const void* b_pr = d_in[7];
  const int* ppi = (const int*)d_in[8];
  const int* dti_drug = (const int*)d_in[9];
  const int* dti_prot = (const int*)d_in[10];

  int n_prot = in_sizes[0] / D;
  int n_drug = in_sizes[1] / D;
  int e_ppi = in_sizes[8] / 2;
  int e_dti = in_sizes[9];
  int e_tot = e_ppi + e_dti;
  int nb = (n_prot + 255) / 256;

  char* ws = (char*)d_ws;
  size_t off = 0;
  auto alloc = [&](size_t bytes) {
    void* p = ws + off;
    off = (off + bytes + 255) & ~(size_t)255;
    return p;
  };
  int* flag = (int*)alloc(256);
  uint* xw2 = (uint*)alloc((size_t)n_prot * 64 * 4);  // 25.6 MB (pre-scaled)
  uint* yd2 = (uint*)alloc((size_t)n_drug * 64 * 4);  //  5.1 MB
  int* deg = (int*)alloc((size_t)n_prot * 4);
  int* cnt = (int*)alloc((size_t)n_prot * 4);
  float* dinv = (float*)alloc((size_t)n_prot * 4);
  float* invcnt = (float*)alloc((size_t)n_prot * 4);
  int* offsets = (int*)alloc((size_t)(n_prot + 1) * 4);
  int* fposp = (int*)alloc((size_t)n_prot * 4);
  int* fposd = (int*)alloc((size_t)n_prot * 4);
  int* bsum = (int*)alloc((size_t)nb * 4);
  uint* csr = (uint*)alloc((size_t)e_tot * 4);  // 9.6 MB

  if (off > ws_size) return;  // insufficient workspace: bail cleanly

  detect_kernel<<<1, 256, 0, stream>>>((const uint*)x_prot, 4096, flag);

  hipMemsetAsync(deg, 0, (size_t)n_prot * 4, stream);
  hipMemsetAsync(cnt, 0, (size_t)n_prot * 4, stream);
  hipMemsetAsync(fposp, 0, (size_t)n_prot * 4, stream);
  hipMemsetAsync(fposd, 0, (size_t)n_prot * 4, stream);

  count_kernel<<<(e_tot + 255) / 256, 256, 0, stream>>>(
      ppi + e_ppi, dti_prot, deg, cnt, e_ppi, e_dti, n_prot);

  block_sum_kernel<<<nb, 256, 0, stream>>>(deg, cnt, n_prot, dinv, invcnt,
                                           bsum);
  scan_bsums_kernel<<<1, 1024, 0, stream>>>(bsum, nb);
  scan_final_kernel<<<nb, 256, 0, stream>>>(deg, cnt, bsum, offsets, n_prot);

  fill_kernel<<<(e_tot + 255) / 256, 256, 0, stream>>>(
      ppi, ppi + e_ppi, dti_drug, dti_prot, offsets, deg, fposp, fposd, csr,
      e_ppi, e_dti, n_prot);

  int gblocks_p = (n_prot + NPB - 1) / NPB;
  int gblocks_d = (n_drug + NPB - 1) / NPB;
  gemm_prot_kernel<<<gblocks_p, 512, 0, stream>>>(
      x_prot, W_gcn, W_pr, b_gcn, b_pr, dinv, xw2, d_out, flag, n_prot);
  gemm_drug_kernel<<<gblocks_d, 512, 0, stream>>>(x_drug, W_td, b_td, yd2,
                                                  flag, n_drug);

  gather_ln_kernel<<<(n_prot + 3) / 4, 256, 0, stream>>>(
      xw2, yd2, dinv, invcnt, offsets, deg, csr, d_out, flag, n_prot);
}